// Round 2
// baseline (17.173 us; speedup 1.0000x reference)
//
#include <hip/hip_runtime.h>

#define NHB 0x7f7f7f7fu
#define HIB 0x80808080u

#if __has_builtin(__builtin_amdgcn_sad_u8)
__device__ __forceinline__ unsigned sad8(unsigned a, unsigned b, unsigned c) {
    return __builtin_amdgcn_sad_u8(a, b, c);
}
#else
__device__ __forceinline__ unsigned sad8(unsigned a, unsigned b, unsigned c) {
    unsigned d;
    asm("v_sad_u8 %0, %1, %2, %3" : "=v"(d) : "v"(a), "v"(b), "v"(c));
    return d;
}
#endif

__device__ __forceinline__ unsigned quantq(float v) {
    // (x * 256).clamp(0, 255) -> truncating int cast (nonneg after clamp)
    v = v * 256.0f;
    v = fminf(fmaxf(v, 0.0f), 255.0f);
    return (unsigned)v;
}

__device__ __forceinline__ unsigned pack4(float a, float b, float c, float d) {
    return quantq(a) | (quantq(b) << 8) | (quantq(c) << 16) | (quantq(d) << 24);
}

// exact per-byte (a+b) & 255, both outputs sharing b's masked form; sad accumulates byte sums
__device__ __forceinline__ void swar2(unsigned a0, unsigned a1, unsigned b,
                                      unsigned& acc0, unsigned& acc1) {
    unsigned mb = b & NHB;
    unsigned s0 = ((a0 & NHB) + mb) ^ ((a0 ^ b) & HIB);
    unsigned s1 = ((a1 & NHB) + mb) ^ ((a1 ^ b) & HIB);
    acc0 = sad8(s0, 0u, acc0);
    acc1 = sad8(s1, 0u, acc1);
}

__global__ __launch_bounds__(512, 2) void adder2d_kernel(
    const float* __restrict__ x, const float* __restrict__ W,
    float* __restrict__ out)
{
    const int tid = threadIdx.x;
    const int bid = blockIdx.x;
    const int n = bid >> 5;   // batch
    const int i = bid & 31;   // output row

    __shared__ unsigned sQW[32 * 72];   // byte-packed qW rows, stride 72 u32 (288 B)
    __shared__ unsigned sQX[32 * 96];   // byte-packed im2col rows, stride 96 u32 (384 B), uint4-col XOR swizzle
    __shared__ unsigned sRowW[768];     // quantized input rows [c][kh][w] as bytes

    // Phase 1a: quantize W -> bytes. u32 m covers W flat [4m..4m+3] (= row f=m/72, word m%72)
    {
        const float4* W4 = (const float4*)W;
        for (int m = tid; m < 2304; m += 512) {
            float4 w = W4[m];
            sQW[m] = pack4(w.x, w.y, w.z, w.w);
        }
    }
    // Phase 1b: quantize input rows i-1..i+1 (zero pad rows -> q=0)
    for (int m = tid; m < 768; m += 512) {
        int c = m / 24;
        int r = m - c * 24;
        int kh = r >> 3;
        int wq = (r & 7) << 2;
        int row = i + kh - 1;
        unsigned pv = 0;
        if (row >= 0 && row < 32) {
            float4 v = *(const float4*)&x[((n * 32 + c) * 32 + row) * 32 + wq];
            pv = pack4(v.x, v.y, v.z, v.w);
        }
        sRowW[m] = pv;
    }
    __syncthreads();

    // Phase 2: build im2col byte rows sQX[j][k], k = c*9+kh*3+kw, swizzled uint4 column
    {
        const unsigned char* sRow = (const unsigned char*)sRowW;
        for (int m = tid; m < 2304; m += 512) {
            int j = m / 72;
            int p = m - j * 72;          // u32 index within row (0..71)
            unsigned v = 0;
#pragma unroll
            for (int e = 0; e < 4; ++e) {
                int k = 4 * p + e;
                int c = k / 9;
                int r = k - 9 * c;
                int kh = r / 3;
                int kw = r - 3 * kh;
                int col = j + kw - 1;
                unsigned bv = (col >= 0 && col < 32) ? (unsigned)sRow[c * 96 + kh * 32 + col] : 0u;
                v |= bv << (8 * e);
            }
            int g = p >> 2, e2 = p & 3;
            sQX[j * 96 + ((g ^ (j & 7)) << 2) + e2] = v;
        }
    }

    // Load this thread's two qW rows into registers (sQW valid since barrier above).
    // Broadcast reads: 2 unique addresses per wave.
    const int f = tid >> 5;   // 0..15 -> outputs f and f+16
    const int j = tid & 31;
    uint4 qa[18], qb[18];
    {
        const uint4* r0 = (const uint4*)&sQW[f * 72];
        const uint4* r1 = (const uint4*)&sQW[(f + 16) * 72];
#pragma unroll
        for (int g = 0; g < 18; ++g) { qa[g] = r0[g]; qb[g] = r1[g]; }
    }
    __syncthreads();

    // Phase 3: 288 terms per output, 2 outputs per thread.
    unsigned acc0 = 0, acc1 = 0;   // max 288*255 = 73440 < 2^32
    const uint4* qx = (const uint4*)&sQX[j * 96];
    const int js = j & 7;
#pragma unroll
    for (int g = 0; g < 18; ++g) {
        uint4 bv = qx[g ^ js];     // conflict-free: lanes j=0..7 hit distinct 4-bank spans
        swar2(qa[g].x, qb[g].x, bv.x, acc0, acc1);
        swar2(qa[g].y, qb[g].y, bv.y, acc0, acc1);
        swar2(qa[g].z, qb[g].z, bv.z, acc0, acc1);
        swar2(qa[g].w, qb[g].w, bv.w, acc0, acc1);
    }

    out[((n * 32 + f) * 32 + i) * 32 + j]        = -(float)acc0 * (1.0f / 256.0f);
    out[((n * 32 + f + 16) * 32 + i) * 32 + j]   = -(float)acc1 * (1.0f / 256.0f);
}

extern "C" void kernel_launch(void* const* d_in, const int* in_sizes, int n_in,
                              void* d_out, int out_size, void* d_ws, size_t ws_size,
                              hipStream_t stream) {
    const float* x = (const float*)d_in[0];   // [8,32,32,32]
    const float* W = (const float*)d_in[1];   // [32,32,3,3]
    float* out = (float*)d_out;               // [8,32,32,32]
    adder2d_kernel<<<256, 512, 0, stream>>>(x, W, out);
}

// Round 3
// 11.974 us; speedup vs baseline: 1.4342x; 1.4342x over previous
//
#include <hip/hip_runtime.h>

#define NHB 0x7f7f7f7fu
#define HIB 0x80808080u

#if __has_builtin(__builtin_amdgcn_sad_u8)
__device__ __forceinline__ unsigned sad8(unsigned a, unsigned b, unsigned c) {
    return __builtin_amdgcn_sad_u8(a, b, c);
}
#else
__device__ __forceinline__ unsigned sad8(unsigned a, unsigned b, unsigned c) {
    unsigned d;
    asm("v_sad_u8 %0, %1, %2, %3" : "=v"(d) : "v"(a), "v"(b), "v"(c));
    return d;
}
#endif

__device__ __forceinline__ unsigned quantq(float v) {
    // (x * 256).clamp(0, 255) -> truncating int cast (nonneg after clamp)
    v = v * 256.0f;
    v = fminf(fmaxf(v, 0.0f), 255.0f);
    return (unsigned)v;
}

__device__ __forceinline__ unsigned pack4(float a, float b, float c, float d) {
    return quantq(a) | (quantq(b) << 8) | (quantq(c) << 16) | (quantq(d) << 24);
}

__global__ __launch_bounds__(1024) void adder2d_kernel(
    const float* __restrict__ x, const float* __restrict__ W,
    float* __restrict__ out)
{
    const int tid = threadIdx.x;
    const int bid = blockIdx.x;
    const int n = bid >> 5;   // batch
    const int i = bid & 31;   // output row

    __shared__ unsigned sQW[32 * 72];   // byte-packed qW rows; 288B row = 18 aligned uint4
    __shared__ unsigned sQX[32 * 96];   // byte-packed im2col rows, 384B stride, granule XOR-swizzled
    __shared__ unsigned sRowW[768];     // quantized input rows [c][kh][w] as bytes

    // Phase 1a: quantize W -> bytes (u32 m covers W flat [4m..4m+3]; row f=m/72)
    {
        const float4* W4 = (const float4*)W;
        for (int m = tid; m < 2304; m += 1024) {
            float4 w = W4[m];
            sQW[m] = pack4(w.x, w.y, w.z, w.w);
        }
    }
    // Phase 1b: quantize input rows i-1..i+1 (out-of-range rows -> q=0)
    if (tid < 768) {
        int m = tid;
        int c = m / 24;
        int r = m - c * 24;
        int kh = r >> 3;
        int wq = (r & 7) << 2;
        int row = i + kh - 1;
        unsigned pv = 0;
        if (row >= 0 && row < 32) {
            float4 v = *(const float4*)&x[((n * 32 + c) * 32 + row) * 32 + wq];
            pv = pack4(v.x, v.y, v.z, v.w);
        }
        sRowW[m] = pv;
    }
    __syncthreads();

    // Phase 2: build im2col byte rows sQX[j][k], k = c*9+kh*3+kw, uint4-granule swizzle g^(j&7)
    {
        const unsigned char* sRow = (const unsigned char*)sRowW;
        for (int m = tid; m < 2304; m += 1024) {
            int j = m / 72;
            int p = m - j * 72;          // u32 index within logical row (0..71)
            unsigned v = 0;
#pragma unroll
            for (int e = 0; e < 4; ++e) {
                int k = 4 * p + e;
                int c = k / 9;
                int rem = k - 9 * c;
                int kh = rem / 3;
                int kw = rem - 3 * kh;
                int col = j + kw - 1;
                unsigned bv = (col >= 0 && col < 32) ? (unsigned)sRow[c * 96 + kh * 32 + col] : 0u;
                v |= bv << (8 * e);
            }
            int g = p >> 2, e2 = p & 3;
            sQX[j * 96 + (((g ^ (j & 7)) << 2) + e2)] = v;   // swizzled granule, fits: <24 granules/row
        }
    }
    __syncthreads();

    // Phase 3: one output per thread. qW reads broadcast (2 addrs/wave); qX reads swizzle-spread.
    const int f = tid >> 5;
    const int j = tid & 31;
    const int js = j & 7;
    const uint4* qwr = (const uint4*)&sQW[f * 72];
    const uint4* qxr = (const uint4*)&sQX[j * 96];
    unsigned acc = 0;   // max 288*255 = 73440 < 2^32
#pragma unroll 6
    for (int g = 0; g < 18; ++g) {
        uint4 a = qwr[g];
        uint4 b = qxr[g ^ js];
        // exact per-byte (a+b)&255 (no cross-byte carry), then sad sums the 4 bytes
        acc = sad8(((a.x & NHB) + (b.x & NHB)) ^ ((a.x ^ b.x) & HIB), 0u, acc);
        acc = sad8(((a.y & NHB) + (b.y & NHB)) ^ ((a.y ^ b.y) & HIB), 0u, acc);
        acc = sad8(((a.z & NHB) + (b.z & NHB)) ^ ((a.z ^ b.z) & HIB), 0u, acc);
        acc = sad8(((a.w & NHB) + (b.w & NHB)) ^ ((a.w ^ b.w) & HIB), 0u, acc);
    }

    out[((n * 32 + f) * 32 + i) * 32 + j] = -(float)acc * (1.0f / 256.0f);
}

extern "C" void kernel_launch(void* const* d_in, const int* in_sizes, int n_in,
                              void* d_out, int out_size, void* d_ws, size_t ws_size,
                              hipStream_t stream) {
    const float* x = (const float*)d_in[0];   // [8,32,32,32]
    const float* W = (const float*)d_in[1];   // [32,32,3,3]
    float* out = (float*)d_out;               // [8,32,32,32]
    adder2d_kernel<<<256, 1024, 0, stream>>>(x, W, out);
}